// Round 1
// 137.960 us; speedup vs baseline: 1.0725x; 1.0725x over previous
//
#include <hip/hip_runtime.h>
#include <hip/hip_bf16.h>

// Problem sizes (fixed by the reference)
#define LROWS 8192
#define BROWS 4096
#define DDIM  1024

typedef __attribute__((ext_vector_type(4)))  int   i32x4;
typedef __attribute__((ext_vector_type(8)))  int   i32x8;
typedef __attribute__((ext_vector_type(16))) float f32x16;

// address-space-qualified pointer typedefs for global_load_lds
typedef const unsigned int __attribute__((address_space(1))) gu32;
typedef unsigned int       __attribute__((address_space(3))) su32;

// pack 4 floats -> 4 fp8 e4m3 bytes (OCP e4m3fn on gfx950)
__device__ inline unsigned int pack_fp8x4(float4 v) {
    unsigned int w = 0;
    w = __builtin_amdgcn_cvt_pk_fp8_f32(v.x, v.y, w, false);  // bytes 0,1
    w = __builtin_amdgcn_cvt_pk_fp8_f32(v.z, v.w, w, true);   // bytes 2,3
    return w;
}

// ---------------- prep: fp32->fp8 cast + pos diag dots + local-loss partials ----------------
// one block per pred/gt row (4096 blocks). Each block ALSO streams its 1/4096 slice of
// q_hat/q_real (512 float4 each) — pure HBM streaming at full rate here (R2/R3 lesson:
// loads inside the GEMM's barrier-drained K-loop can't hide). 104 MB of mandatory
// traffic at ~6.1 TB/s = HBM roofline (R5 measured). Block 0 zero-inits out.
__global__ __launch_bounds__(256) void prep_kernel(
    const float4* __restrict__ pred,
    const float4* __restrict__ gt,
    unsigned int* __restrict__ opred,   // fp8, 256 uints per row
    unsigned int* __restrict__ ogt,
    const float4* __restrict__ qh,
    const float4* __restrict__ qr,
    float* __restrict__ pos,
    float* __restrict__ lpart,          // [4096] per-block local-loss partials
    float* __restrict__ out) {
    __shared__ float sred[4], sred2[4];
    const int row = blockIdx.x;
    const int t = threadIdx.x;
    if (row == 0 && t == 0) out[0] = 0.0f;

    const int idx = row * 256 + t;
    float4 p = pred[idx];
    float4 g = gt[idx];
    opred[idx] = pack_fp8x4(p);
    ogt[idx]   = pack_fp8x4(g);
    float s = p.x * g.x + p.y * g.y + p.z * g.z + p.w * g.w;

    // q slice: 512 float4 per block, 2 per thread
    const int qi = row * 512 + t;
    float4 a0 = qh[qi], b0 = qr[qi];
    float4 a1 = qh[qi + 256], b1 = qr[qi + 256];
    float ls = a0.x * b0.x + a0.y * b0.y + a0.z * b0.z + a0.w * b0.w
             + a1.x * b1.x + a1.y * b1.y + a1.z * b1.z + a1.w * b1.w;

    #pragma unroll
    for (int o = 32; o > 0; o >>= 1) {
        s  += __shfl_down(s, o, 64);
        ls += __shfl_down(ls, o, 64);
    }
    if ((t & 63) == 0) { sred[t >> 6] = s; sred2[t >> 6] = ls; }
    __syncthreads();
    if (t == 0) {
        pos[row]   = sred[0] + sred[1] + sred[2] + sred[3];
        lpart[row] = sred2[0] + sred2[1] + sred2[2] + sred2[3];
    }
}

// ---------------- hinge GEMM v2 (MX fp8): 256x256 tile, 8 waves, ping-pong dbuf ----------------
// R7 restructure. Old 128²/4-wave/2x2 was at 22% of the 4.65 PF MX-fp8 ceiling because
// (a) 2 KB LDS-read per mfma (32 FLOP/B) put ds_read at parity with the matrix pipe and
// (b) stage->drain->compute serialization relied on cross-block overlap that didn't hide.
// Now: 256x256 block tile (grid 16x16 = 256 = 1 block/CU), 8 waves (2x4), wave tile
// 128x64 = 4x2 of mfma_scale_32x32x64 -> 1.5 KB LDS per mfma (LDS ceiling now above MFMA).
// BK=128 double-buffered: 4 x 32 KB = 128 KB dynamic LDS. T3-minimum schedule: issue
// next tile's global_load_lds BEFORE ds_read+MFMA of current tile; ONE __syncthreads per
// K-step (its vmcnt(0) drain lands AFTER ~2200 cyc of compute, so staging is hidden —
// the dbuf that was neutral at 4 blocks/CU (R6) is the hiding mechanism at 1 block/CU).
// Same 16B-unit XOR-by-(row&7) LDS swizzle as v1 (proven conflict-free, absmax 0).
// XCD-chunked swizzle: each XCD owns a 4bm x 8bn region (A dup x2, B dup x4 from HBM).
__global__ __launch_bounds__(512, 2) void hinge_gemm(
    const unsigned char* __restrict__ A,    // pred_fp8 [BROWS][DDIM] row-major, 1024 B/row
    const unsigned char* __restrict__ Bm,   // gt_fp8
    const float* __restrict__ pos,          // [BROWS]
    const float* __restrict__ lpart,        // [4096]
    float* __restrict__ out) {
    extern __shared__ unsigned char smem[];
    unsigned char* const As = smem;                       // [2][256*128] = 64 KB
    unsigned char* const Bs = smem + 65536;               // [2][256*128] = 64 KB
    float* const pos_s = (float*)(smem + 131072);         // 256 floats
    float* const sred  = (float*)(smem + 131072 + 1024);  // 8 floats

    // XCD-chunked swizzle: dispatch order round-robins XCDs (orig % 8). Give XCD k the
    // region bm in [ (k>>1)*4, +4 ), bn in [ (k&1)*8, +8 ) -> 32 blocks, ~3 MB L2 footprint.
    const int orig = blockIdx.x;
    const int xk = orig & 7, xj = orig >> 3;      // xj: 0..31 within XCD, bn-fastest
    const int bm = (xk >> 1) * 4 + (xj >> 3);     // 0..15
    const int bn = (xk & 1) * 8 + (xj & 7);       // 0..15

    const int tid = threadIdx.x;
    const int lane = tid & 63;
    const int wave = tid >> 6;   // 0..7
    const int wm = wave >> 2;    // 0..1  wave row (128 rows each)
    const int wn = wave & 3;     // 0..3  wave col (64 cols each)

    if (tid < 256) pos_s[tid] = pos[bm * 256 + tid];

    // staging: 32 chunks of 1 KB per matrix (256 rows x 128 B). wave w stages chunks
    // w*4..w*4+3 of A and of B; chunk c = rows c*8..c*8+7. lane l -> row_in_chunk l>>3,
    // phys 16B unit l&7; fetches LOGICAL unit (l&7)^(l>>3) so phys_unit = log_unit ^ (row&7).
    const int grow = lane >> 3;                 // 0..7
    const int usw  = (lane & 7) ^ grow;         // logical unit this lane fetches

    const unsigned char* Abase = A  + (size_t)(bm * 256) * DDIM;
    const unsigned char* Bbase = Bm + (size_t)(bn * 256) * DDIM;

    f32x16 acc[4][2];
    #pragma unroll
    for (int i = 0; i < 4; i++)
        #pragma unroll
        for (int j = 0; j < 2; j++)
            #pragma unroll
            for (int r = 0; r < 16; r++) acc[i][j][r] = 0.0f;

    const int sc1 = 0x7f7f7f7f;        // E8M0 1.0 in every byte
    const int mrow = lane & 31;        // m (or n) within 32x32 tile
    const int kh = lane >> 5;          // 0..1: which 32-byte k-half of the mfma's K=64

    auto stage = [&](int buf, int k0) {
        #pragma unroll
        for (int i = 0; i < 4; i++) {
            const int c = wave * 4 + i;         // chunk 0..31
            const int row = c * 8 + grow;       // tile row 0..255
            __builtin_amdgcn_global_load_lds(
                (gu32*)(Abase + (size_t)row * DDIM + k0 + usw * 16),
                (su32*)(As + buf * 32768 + c * 1024), 16, 0, 0);
            __builtin_amdgcn_global_load_lds(
                (gu32*)(Bbase + (size_t)row * DDIM + k0 + usw * 16),
                (su32*)(Bs + buf * 32768 + c * 1024), 16, 0, 0);
        }
    };

    auto compute = [&](int buf) {
        const unsigned char* Ab = As + buf * 32768;
        const unsigned char* Bb = Bs + buf * 32768;
        #pragma unroll
        for (int h = 0; h < 2; h++) {          // two K=64 mfma steps per staged BK=128
            const int u0 = h * 4 + kh * 2;     // logical 16B unit of this lane's k-block
            i32x8 af[4];
            i32x8 bg[2];
            #pragma unroll
            for (int mt = 0; mt < 4; mt++) {
                const int r = wm * 128 + mt * 32 + mrow;
                i32x4 x0 = *(const i32x4*)&Ab[r * 128 + ((u0    ) ^ (r & 7)) * 16];
                i32x4 x1 = *(const i32x4*)&Ab[r * 128 + ((u0 + 1) ^ (r & 7)) * 16];
                af[mt] = __builtin_shufflevector(x0, x1, 0, 1, 2, 3, 4, 5, 6, 7);
            }
            #pragma unroll
            for (int nt = 0; nt < 2; nt++) {
                const int r = wn * 64 + nt * 32 + mrow;
                i32x4 x0 = *(const i32x4*)&Bb[r * 128 + ((u0    ) ^ (r & 7)) * 16];
                i32x4 x1 = *(const i32x4*)&Bb[r * 128 + ((u0 + 1) ^ (r & 7)) * 16];
                bg[nt] = __builtin_shufflevector(x0, x1, 0, 1, 2, 3, 4, 5, 6, 7);
            }
            __builtin_amdgcn_s_setprio(1);
            #pragma unroll
            for (int mt = 0; mt < 4; mt++)
                #pragma unroll
                for (int nt = 0; nt < 2; nt++)
                    acc[mt][nt] = __builtin_amdgcn_mfma_scale_f32_32x32x64_f8f6f4(
                        af[mt], bg[nt], acc[mt][nt],
                        0, 0,          // cbsz = A fmt fp8(e4m3), blgp = B fmt fp8
                        0, sc1,        // scale_a opsel, scale_a (1.0)
                        0, sc1);       // scale_b opsel, scale_b (1.0)
            __builtin_amdgcn_s_setprio(0);
        }
    };

    // T3-minimum pipeline: prologue stage; per step {stage next | compute cur | sync}.
    // The single __syncthreads' vmcnt(0) drains staging that had the whole compute
    // phase in flight. Hazard check: stage(p^1) at step t overwrites the buffer read at
    // step t-1, and every wave passed the t-1 sync (lgkmcnt drained) before any t-issue.
    stage(0, 0);
    __syncthreads();
    int p = 0;
    for (int t = 0; t < 7; t++) {
        stage(p ^ 1, (t + 1) * 128);
        compute(p);
        __syncthreads();
        p ^= 1;
    }
    compute(p);   // last tile, no prefetch

    // epilogue: hinge + block reduction + local-loss partial fold
    // 32x32 C/D layout: col = lane&31 (gt idx), row = (reg&3) + 8*(reg>>2) + 4*(lane>>5)
    // (pred idx) [verified m74/m101; dtype-independent; v1 passed with absmax 0]
    float s = 0.0f;
    const int rq = 4 * kh;
    #pragma unroll
    for (int mt = 0; mt < 4; mt++) {
        #pragma unroll
        for (int nt = 0; nt < 2; nt++) {
            #pragma unroll
            for (int i = 0; i < 16; i++) {
                const int lr = wm * 128 + mt * 32 + (i & 3) + 8 * (i >> 2) + rq;
                const float v = acc[mt][nt][i] - pos_s[lr] + 1.0f;
                s += fmaxf(v, 0.0f);
            }
        }
    }
    #pragma unroll
    for (int o = 32; o > 0; o >>= 1) s += __shfl_down(s, o, 64);
    if (lane == 0) sred[wave] = s;
    __syncthreads();
    if (tid == 0) {
        float tot = 0.0f;
        #pragma unroll
        for (int w = 0; w < 8; w++) tot += sred[w];
        const int bid = (bm * 16 + bn) * 16;   // 16 lpart entries per block (4096/256)
        float lp = 0.0f;
        #pragma unroll
        for (int i = 0; i < 16; i++) lp += lpart[bid + i];
        atomicAdd(out, tot - lp * (1.0f / (float)LROWS));
    }
}

extern "C" void kernel_launch(void* const* d_in, const int* in_sizes, int n_in,
                              void* d_out, int out_size, void* d_ws, size_t ws_size,
                              hipStream_t stream) {
    const float* q_hat  = (const float*)d_in[0];
    const float* q_real = (const float*)d_in[1];
    const float* gt     = (const float*)d_in[2];  // encoded_gt
    const float* pred   = (const float*)d_in[3];  // encoded_pred
    float* out = (float*)d_out;

    // workspace layout: pred_fp8 (4MB) | gt_fp8 (4MB) | pos (16KB) | lpart (16KB)
    char* ws = (char*)d_ws;
    unsigned char* pred_8 = (unsigned char*)ws;
    unsigned char* gt_8   = (unsigned char*)(ws + (size_t)BROWS * DDIM);
    float* pos   = (float*)(ws + (size_t)2 * BROWS * DDIM);
    float* lpart = (float*)(ws + (size_t)2 * BROWS * DDIM + BROWS * 4);

    hipLaunchKernelGGL(prep_kernel, dim3(BROWS), dim3(256), 0, stream,
                       (const float4*)pred, (const float4*)gt,
                       (unsigned int*)pred_8, (unsigned int*)gt_8,
                       (const float4*)q_hat, (const float4*)q_real,
                       pos, lpart, out);

    // 128 KB tiles + 1 KB pos + 32 B sred of dynamic LDS (1 block/CU, 160 KB available)
    const size_t lds_bytes = 131072 + 1024 + 32;
    hipLaunchKernelGGL(hinge_gemm, dim3(256), dim3(512), lds_bytes, stream,
                       pred_8, gt_8, pos, lpart, out);
}

// Round 2
// 131.238 us; speedup vs baseline: 1.1275x; 1.0512x over previous
//
#include <hip/hip_runtime.h>
#include <hip/hip_bf16.h>

// Problem sizes (fixed by the reference)
#define LROWS 8192
#define BROWS 4096
#define DDIM  1024

typedef __attribute__((ext_vector_type(4)))  int   i32x4;
typedef __attribute__((ext_vector_type(8)))  int   i32x8;
typedef __attribute__((ext_vector_type(16))) float f32x16;

// address-space-qualified pointer typedefs for global_load_lds
typedef const unsigned int __attribute__((address_space(1))) gu32;
typedef unsigned int       __attribute__((address_space(3))) su32;

// pack 4 floats -> 4 fp8 e4m3 bytes (OCP e4m3fn on gfx950)
__device__ inline unsigned int pack_fp8x4(float4 v) {
    unsigned int w = 0;
    w = __builtin_amdgcn_cvt_pk_fp8_f32(v.x, v.y, w, false);  // bytes 0,1
    w = __builtin_amdgcn_cvt_pk_fp8_f32(v.z, v.w, w, true);   // bytes 2,3
    return w;
}

// ---------------- prep v3: fp32->fp8 cast + pos diag dots ONLY ----------------
// R8: the q_hat/q_real stream (64 MB, independent of the GEMM dep chain) moved into
// the hinge K-loop where it hides under MFMA compute. Prep is now 32 MB read +
// 8 MB write of mandatory cast traffic ~= 6.5-7 us at the measured ~6.1 TB/s.
// Block 0 zero-inits out.
__global__ __launch_bounds__(256) void prep_kernel(
    const float4* __restrict__ pred,
    const float4* __restrict__ gt,
    unsigned int* __restrict__ opred,   // fp8, 256 uints per row
    unsigned int* __restrict__ ogt,
    float* __restrict__ pos,
    float* __restrict__ out) {
    __shared__ float sred[4];
    const int row = blockIdx.x;
    const int t = threadIdx.x;
    if (row == 0 && t == 0) out[0] = 0.0f;

    const int idx = row * 256 + t;
    float4 p = pred[idx];
    float4 g = gt[idx];
    opred[idx] = pack_fp8x4(p);
    ogt[idx]   = pack_fp8x4(g);
    float s = p.x * g.x + p.y * g.y + p.z * g.z + p.w * g.w;

    #pragma unroll
    for (int o = 32; o > 0; o >>= 1) s += __shfl_down(s, o, 64);
    if ((t & 63) == 0) sred[t >> 6] = s;
    __syncthreads();
    if (t == 0) pos[row] = sred[0] + sred[1] + sred[2] + sred[3];
}

// ---------------- hinge GEMM v3 (MX fp8): 256x256 tile + folded q-stream ----------------
// Structure unchanged from R7 (measured win): 256x256 block tile, grid 256 (1 block/CU),
// 8 waves (2x4), wave tile 128x64 = 4x2 of mfma_scale_32x32x64 (fp8, E8M0 scale=1.0),
// BK=128 ping-pong dbuf (128 KB LDS), stage-before-compute, one __syncthreads/step.
// R8 addition: each block streams its 1/256 slice of q_hat/q_real (256 KB) through the
// K-loop — 2 float4 per array per thread per step, issued at step start so the existing
// vmcnt(0)-drain barrier gives them the whole ~2200-cyc MFMA phase to land (HBM latency
// ~900 cyc). Per-step demand ~2.8 TB/s against an otherwise-idle HBM pipe.
// Software-pipelined one step deep with NAMED registers (rule #20: no runtime-indexed
// register arrays). Same 16B-unit XOR-by-(row&7) LDS swizzle (proven conflict-free).
__global__ __launch_bounds__(512, 2) void hinge_gemm(
    const unsigned char* __restrict__ A,    // pred_fp8 [BROWS][DDIM] row-major, 1024 B/row
    const unsigned char* __restrict__ Bm,   // gt_fp8
    const float* __restrict__ pos,          // [BROWS]
    const float4* __restrict__ qh,          // q_hat  as float4[2M]
    const float4* __restrict__ qr,          // q_real as float4[2M]
    float* __restrict__ out) {
    extern __shared__ unsigned char smem[];
    unsigned char* const As = smem;                       // [2][256*128] = 64 KB
    unsigned char* const Bs = smem + 65536;               // [2][256*128] = 64 KB
    float* const pos_s = (float*)(smem + 131072);         // 256 floats
    float* const sred  = (float*)(smem + 132096);         // 8 floats
    float* const sred2 = (float*)(smem + 132128);         // 8 floats

    // XCD-chunked swizzle: dispatch order round-robins XCDs (orig % 8). Give XCD k the
    // region bm in [ (k>>1)*4, +4 ), bn in [ (k&1)*8, +8 ) -> 32 blocks, ~3 MB L2 footprint.
    const int orig = blockIdx.x;
    const int xk = orig & 7, xj = orig >> 3;      // xj: 0..31 within XCD, bn-fastest
    const int bm = (xk >> 1) * 4 + (xj >> 3);     // 0..15
    const int bn = (xk & 1) * 8 + (xj & 7);       // 0..15

    const int tid = threadIdx.x;
    const int lane = tid & 63;
    const int wave = tid >> 6;   // 0..7
    const int wm = wave >> 2;    // 0..1  wave row (128 rows each)
    const int wn = wave & 3;     // 0..3  wave col (64 cols each)

    if (tid < 256) pos_s[tid] = pos[bm * 256 + tid];

    // staging geometry (unchanged): wave w stages chunks w*4..w*4+3 of A and of B;
    // chunk c = rows c*8..c*8+7; lane l -> row_in_chunk l>>3, fetches logical 16B unit
    // (l&7)^(l>>3) so the tile lands with phys_unit = log_unit ^ (row&7).
    const int grow = lane >> 3;                 // 0..7
    const int usw  = (lane & 7) ^ grow;         // logical unit this lane fetches

    const unsigned char* Abase = A  + (size_t)(bm * 256) * DDIM;
    const unsigned char* Bbase = Bm + (size_t)(bn * 256) * DDIM;

    // q slice for this block: 8192 float4 per array (flat partition by orig)
    const float4* qhb = qh + (size_t)orig * 8192;
    const float4* qrb = qr + (size_t)orig * 8192;

    f32x16 acc[4][2];
    #pragma unroll
    for (int i = 0; i < 4; i++)
        #pragma unroll
        for (int j = 0; j < 2; j++)
            #pragma unroll
            for (int r = 0; r < 16; r++) acc[i][j][r] = 0.0f;

    const int sc1 = 0x7f7f7f7f;        // E8M0 1.0 in every byte
    const int mrow = lane & 31;        // m (or n) within 32x32 tile
    const int kh = lane >> 5;          // 0..1: which 32-byte k-half of the mfma's K=64

    auto stage = [&](int buf, int k0) {
        #pragma unroll
        for (int i = 0; i < 4; i++) {
            const int c = wave * 4 + i;         // chunk 0..31
            const int row = c * 8 + grow;       // tile row 0..255
            __builtin_amdgcn_global_load_lds(
                (gu32*)(Abase + (size_t)row * DDIM + k0 + usw * 16),
                (su32*)(As + buf * 32768 + c * 1024), 16, 0, 0);
            __builtin_amdgcn_global_load_lds(
                (gu32*)(Bbase + (size_t)row * DDIM + k0 + usw * 16),
                (su32*)(Bs + buf * 32768 + c * 1024), 16, 0, 0);
        }
    };

    auto compute = [&](int buf) {
        const unsigned char* Ab = As + buf * 32768;
        const unsigned char* Bb = Bs + buf * 32768;
        #pragma unroll
        for (int h = 0; h < 2; h++) {          // two K=64 mfma steps per staged BK=128
            const int u0 = h * 4 + kh * 2;     // logical 16B unit of this lane's k-block
            i32x8 af[4];
            i32x8 bg[2];
            #pragma unroll
            for (int mt = 0; mt < 4; mt++) {
                const int r = wm * 128 + mt * 32 + mrow;
                i32x4 x0 = *(const i32x4*)&Ab[r * 128 + ((u0    ) ^ (r & 7)) * 16];
                i32x4 x1 = *(const i32x4*)&Ab[r * 128 + ((u0 + 1) ^ (r & 7)) * 16];
                af[mt] = __builtin_shufflevector(x0, x1, 0, 1, 2, 3, 4, 5, 6, 7);
            }
            #pragma unroll
            for (int nt = 0; nt < 2; nt++) {
                const int r = wn * 64 + nt * 32 + mrow;
                i32x4 x0 = *(const i32x4*)&Bb[r * 128 + ((u0    ) ^ (r & 7)) * 16];
                i32x4 x1 = *(const i32x4*)&Bb[r * 128 + ((u0 + 1) ^ (r & 7)) * 16];
                bg[nt] = __builtin_shufflevector(x0, x1, 0, 1, 2, 3, 4, 5, 6, 7);
            }
            __builtin_amdgcn_s_setprio(1);
            #pragma unroll
            for (int mt = 0; mt < 4; mt++)
                #pragma unroll
                for (int nt = 0; nt < 2; nt++)
                    acc[mt][nt] = __builtin_amdgcn_mfma_scale_f32_32x32x64_f8f6f4(
                        af[mt], bg[nt], acc[mt][nt],
                        0, 0,          // cbsz = A fmt fp8(e4m3), blgp = B fmt fp8
                        0, sc1,        // scale_a opsel, scale_a (1.0)
                        0, sc1);       // scale_b opsel, scale_b (1.0)
            __builtin_amdgcn_s_setprio(0);
        }
    };

    // q-stream registers, pipelined one K-step deep (named, not arrays — rule #20)
    float ls = 0.0f;
    float4 ch0, ch1, cr0, cr1;   // current (ready to accumulate)
    float4 nh0, nh1, nr0, nr1;   // next (in flight)

    // pipeline: prologue stage + q chunk 0; per step {stage next | q-load next |
    // q-accum cur | compute cur | sync}. The single __syncthreads' vmcnt(0) drains
    // staging AND q-loads that had the whole compute phase in flight. WAR on the LDS
    // ping-pong is protected by the barrier sitting after compute (unchanged from R7).
    stage(0, 0);
    ch0 = qhb[tid];       ch1 = qhb[tid + 512];
    cr0 = qrb[tid];       cr1 = qrb[tid + 512];
    __syncthreads();
    int p = 0;
    for (int t = 0; t < 7; t++) {
        stage(p ^ 1, (t + 1) * 128);
        const int qo = (t + 1) * 1024 + tid;
        nh0 = qhb[qo];       nh1 = qhb[qo + 512];
        nr0 = qrb[qo];       nr1 = qrb[qo + 512];
        ls += ch0.x * cr0.x + ch0.y * cr0.y + ch0.z * cr0.z + ch0.w * cr0.w
            + ch1.x * cr1.x + ch1.y * cr1.y + ch1.z * cr1.z + ch1.w * cr1.w;
        compute(p);
        __syncthreads();
        ch0 = nh0; ch1 = nh1; cr0 = nr0; cr1 = nr1;
        p ^= 1;
    }
    ls += ch0.x * cr0.x + ch0.y * cr0.y + ch0.z * cr0.z + ch0.w * cr0.w
        + ch1.x * cr1.x + ch1.y * cr1.y + ch1.z * cr1.z + ch1.w * cr1.w;
    compute(p);   // last tile, no prefetch

    // epilogue: hinge + block reduction + local-loss fold
    // 32x32 C/D layout: col = lane&31 (gt idx), row = (reg&3) + 8*(reg>>2) + 4*(lane>>5)
    // (pred idx) [verified m74/m101; dtype-independent; R5/R7 passed with absmax 0]
    float s = 0.0f;
    const int rq = 4 * kh;
    #pragma unroll
    for (int mt = 0; mt < 4; mt++) {
        #pragma unroll
        for (int nt = 0; nt < 2; nt++) {
            #pragma unroll
            for (int i = 0; i < 16; i++) {
                const int lr = wm * 128 + mt * 32 + (i & 3) + 8 * (i >> 2) + rq;
                const float v = acc[mt][nt][i] - pos_s[lr] + 1.0f;
                s += fmaxf(v, 0.0f);
            }
        }
    }
    #pragma unroll
    for (int o = 32; o > 0; o >>= 1) {
        s  += __shfl_down(s, o, 64);
        ls += __shfl_down(ls, o, 64);
    }
    if (lane == 0) { sred[wave] = s; sred2[wave] = ls; }
    __syncthreads();
    if (tid == 0) {
        float tot = 0.0f, lp = 0.0f;
        #pragma unroll
        for (int w = 0; w < 8; w++) { tot += sred[w]; lp += sred2[w]; }
        atomicAdd(out, tot - lp * (1.0f / (float)LROWS));
    }
}

extern "C" void kernel_launch(void* const* d_in, const int* in_sizes, int n_in,
                              void* d_out, int out_size, void* d_ws, size_t ws_size,
                              hipStream_t stream) {
    const float* q_hat  = (const float*)d_in[0];
    const float* q_real = (const float*)d_in[1];
    const float* gt     = (const float*)d_in[2];  // encoded_gt
    const float* pred   = (const float*)d_in[3];  // encoded_pred
    float* out = (float*)d_out;

    // workspace layout: pred_fp8 (4MB) | gt_fp8 (4MB) | pos (16KB)
    char* ws = (char*)d_ws;
    unsigned char* pred_8 = (unsigned char*)ws;
    unsigned char* gt_8   = (unsigned char*)(ws + (size_t)BROWS * DDIM);
    float* pos   = (float*)(ws + (size_t)2 * BROWS * DDIM);

    hipLaunchKernelGGL(prep_kernel, dim3(BROWS), dim3(256), 0, stream,
                       (const float4*)pred, (const float4*)gt,
                       (unsigned int*)pred_8, (unsigned int*)gt_8,
                       pos, out);

    // 128 KB tiles + 1 KB pos + 2x32 B reduction scratch of dynamic LDS (1 block/CU)
    const size_t lds_bytes = 131072 + 1024 + 64;
    hipLaunchKernelGGL(hinge_gemm, dim3(256), dim3(512), lds_bytes, stream,
                       pred_8, gt_8, pos,
                       (const float4*)q_hat, (const float4*)q_real, out);
}